// Round 7
// baseline (514.564 us; speedup 1.0000x reference)
//
#include <hip/hip_runtime.h>
#include <hip/hip_bf16.h>
#include <math.h>

#define N_NODES 100000
#define F_IN    500
#define HID     64
#define NCLS    40                         // zs rows: 40 cols = 80 B, 16B-aligned
#define NBKT    ((N_NODES + 255) / 256)    // 391 coarse buckets of 256 nodes
#define CAP     8192                       // static slab capacity per bucket (mean 4096)
#define FILL_BLKS 512
#define PREP_BLKS 128                      // 128*256 = 32768 = 64*512 W1T elements
#define GEMM_BLKS ((N_NODES + 127) / 128)  // 782

typedef __attribute__((ext_vector_type(8))) short short8v;
typedef __attribute__((ext_vector_type(4))) float floatx4;
typedef unsigned short ushort_t;
typedef unsigned int uint_t;

__device__ __forceinline__ float bflo(uint_t u) {
    union { uint_t i; float f; } v; v.i = u << 16; return v.f;
}
__device__ __forceinline__ float bfhi(uint_t u) {
    union { uint_t i; float f; } v; v.i = u & 0xffff0000u; return v.f;
}
__device__ __forceinline__ ushort_t f2bf(float f) {
    __hip_bfloat16 b = __float2bfloat16(f);
    return *(ushort_t*)&b;
}
__device__ __forceinline__ uint_t pack2(float a, float b) {
    return (uint_t)f2bf(a) | ((uint_t)f2bf(b) << 16);
}

// ============ kernel 1: fill (blocks [0,FILL_BLKS)) ∥ W1T prep (rest) ============
// bcount must be zeroed (hipMemsetAsync) before this kernel.
__global__ __launch_bounds__(256) void k1_fill_prep(const int* __restrict__ src,
                                                    const int* __restrict__ dst,
                                                    int* __restrict__ bcount,
                                                    int* __restrict__ pairs,
                                                    const float* __restrict__ W1,
                                                    ushort_t* __restrict__ W1T, int E) {
    if (blockIdx.x >= FILL_BLKS) {
        // W1 transpose -> bf16, K padded to 512
        int idx = (blockIdx.x - FILL_BLKS) * 256 + threadIdx.x;   // 0..32767
        int nn = idx >> 9;
        int k  = idx & 511;
        float v = (k < F_IN) ? W1[(size_t)k * HID + nn] : 0.0f;
        W1T[idx] = f2bf(v);
        return;
    }
    // ---- fill: count + reserve + scatter into static slabs ----
    __shared__ int c[NBKT];
    __shared__ int base[NBKT];
    for (int i = threadIdx.x; i < NBKT; i += 256) c[i] = 0;
    __syncthreads();
    int chunk = (E + FILL_BLKS - 1) / FILL_BLKS;
    int lo = blockIdx.x * chunk;
    int hi = min(lo + chunk, E);
    for (int e = lo + threadIdx.x; e < hi; e += 256) atomicAdd(&c[dst[e] >> 8], 1);
    __syncthreads();
    for (int i = threadIdx.x; i < NBKT; i += 256) {
        int nn = c[i];
        base[i] = nn ? (i * CAP + atomicAdd(&bcount[i], nn)) : 0;
    }
    __syncthreads();
    for (int i = threadIdx.x; i < NBKT; i += 256) c[i] = 0;
    __syncthreads();
    for (int e = lo + threadIdx.x; e < hi; e += 256) {
        int d = dst[e];
        int b = d >> 8;
        int p = base[b] + atomicAdd(&c[b], 1);
        // defensive: never write outside this bucket's slab
        if (p < (b + 1) * CAP) pairs[p] = src[e] | ((d & 255) << 17);   // src < 2^17
    }
}

// ============ b_fine: per-bucket CSR finalize ============
__global__ __launch_bounds__(256) void b_fine_kernel(const int* __restrict__ pairs,
                                                     const int* __restrict__ bcount,
                                                     int2* __restrict__ rse,
                                                     int* __restrict__ col,
                                                     float* __restrict__ dinv, int n) {
    __shared__ int w[CAP];
    __shared__ int cnt[256];
    __shared__ int scn[256];
    __shared__ int cur[256];
    int b = blockIdx.x;
    int nb0 = b << 8;
    int nodes = min(256, n - nb0);
    int g0 = b * CAP;
    int size = min(bcount[b], CAP);
    int tid = threadIdx.x;

    for (int i = tid; i < size; i += 256) w[i] = pairs[g0 + i];
    cnt[tid] = 0;
    __syncthreads();
    for (int i = tid; i < size; i += 256) atomicAdd(&cnt[w[i] >> 17], 1);
    __syncthreads();
    int v = cnt[tid];
    scn[tid] = v;
    __syncthreads();
    for (int off = 1; off < 256; off <<= 1) {
        int t = (tid >= off) ? scn[tid - off] : 0;
        __syncthreads();
        scn[tid] += t;
        __syncthreads();
    }
    int excl = scn[tid] - v;
    cur[tid] = g0 + excl;
    if (tid < nodes) {
        rse[nb0 + tid] = make_int2(g0 + excl, g0 + excl + v);
        dinv[nb0 + tid] = rsqrtf((float)(v + 1));
    }
    __syncthreads();
    for (int i = tid; i < size; i += 256) {
        int word = w[i];
        int pos = atomicAdd(&cur[word >> 17], 1);
        col[pos] = word & 0x1FFFF;
    }
}

// ============ GEMM1 (MFMA bf16, double-buffered): xws = (x @ W1)*dinv, bf16 ============
__global__ __launch_bounds__(256) void gemm1_mfma(const float* __restrict__ x,
                                                  const ushort_t* __restrict__ W1T,
                                                  const float* __restrict__ dinv,
                                                  ushort_t* __restrict__ xws, int n) {
    __shared__ __align__(16) ushort_t As[2][128 * 72];
    const int tid  = threadIdx.x;
    const int wave = tid >> 6;
    const int lane = tid & 63;
    const int m16  = lane & 15;
    const int q    = lane >> 4;
    const int r0   = blockIdx.x * 128;

    floatx4 acc[2][4];
#pragma unroll
    for (int i = 0; i < 2; i++)
#pragma unroll
        for (int j = 0; j < 4; j++) acc[i][j] = (floatx4){0.f, 0.f, 0.f, 0.f};

    const int kg    = tid & 15;   // k-quad (4 floats)
    const int rbase = tid >> 4;   // 0..15

    floatx4 pf[8];
    const floatx4 zero4 = (floatx4){0.f, 0.f, 0.f, 0.f};
    {
        const int k4 = kg * 4;
#pragma unroll
        for (int rr = 0; rr < 8; rr++) {
            int gr = r0 + rbase + rr * 16;
            pf[rr] = (gr < n) ? __builtin_nontemporal_load((const floatx4*)&x[(size_t)gr * F_IN + k4])
                              : zero4;
        }
#pragma unroll
        for (int rr = 0; rr < 8; rr++) {
            int row = rbase + rr * 16;
            *(uint2*)&As[0][row * 72 + kg * 4] =
                make_uint2(pack2(pf[rr][0], pf[rr][1]), pack2(pf[rr][2], pf[rr][3]));
        }
    }
    __syncthreads();

    for (int it = 0; it < 8; it++) {
        const int cur = it & 1;
        if (it < 7) {
            const int k4 = (it + 1) * 64 + kg * 4;
            const bool kok = (k4 < F_IN);
#pragma unroll
            for (int rr = 0; rr < 8; rr++) {
                int gr = r0 + rbase + rr * 16;
                pf[rr] = (kok && gr < n)
                           ? __builtin_nontemporal_load((const floatx4*)&x[(size_t)gr * F_IN + k4])
                           : zero4;
            }
        }
        const int kb = it * 64;
#pragma unroll
        for (int kt = 0; kt < 2; kt++) {
            const int ko = kt * 32 + q * 8;
            short8v a0 = *(const short8v*)&As[cur][(wave * 32 + m16) * 72 + ko];
            short8v a1 = *(const short8v*)&As[cur][(wave * 32 + 16 + m16) * 72 + ko];
#pragma unroll
            for (int nt = 0; nt < 4; nt++) {
                short8v b = *(const short8v*)&W1T[(size_t)(nt * 16 + m16) * 512 + kb + ko];
                acc[0][nt] = __builtin_amdgcn_mfma_f32_16x16x32_bf16(a0, b, acc[0][nt], 0, 0, 0);
                acc[1][nt] = __builtin_amdgcn_mfma_f32_16x16x32_bf16(a1, b, acc[1][nt], 0, 0, 0);
            }
        }
        if (it < 7) {
#pragma unroll
            for (int rr = 0; rr < 8; rr++) {
                int row = rbase + rr * 16;
                *(uint2*)&As[1 - cur][row * 72 + kg * 4] =
                    make_uint2(pack2(pf[rr][0], pf[rr][1]), pack2(pf[rr][2], pf[rr][3]));
            }
            __syncthreads();
        }
    }

    // epilogue: write dinv-PRE-SCALED bf16
#pragma unroll
    for (int mt = 0; mt < 2; mt++) {
#pragma unroll
        for (int i = 0; i < 4; i++) {
            int gr = r0 + wave * 32 + mt * 16 + q * 4 + i;
            if (gr < n) {
                float di = dinv[gr];
#pragma unroll
                for (int nt = 0; nt < 4; nt++) {
                    xws[(size_t)gr * HID + nt * 16 + m16] = f2bf(acc[mt][nt][i] * di);
                }
            }
        }
    }
}

// ============ agg1z: aggregate + relu + FUSED W2 matvec -> zs (40 cols, bf16) ============
// h[d] = relu(dinv[d]*(Σ xws[s] + xws[d]) + b1)        (f32, in-register)
// zs[d] = (h[d]*dinv[d]) @ W2                          (f32 matvec, bf16 store)
__global__ __launch_bounds__(256) void agg1z_kernel(const ushort_t* __restrict__ xws,
                                                    const int* __restrict__ col,
                                                    const int2* __restrict__ rse,
                                                    const float* __restrict__ dinv,
                                                    const float* __restrict__ b1,
                                                    const float* __restrict__ W2,
                                                    ushort_t* __restrict__ zs, int n) {
    __shared__ float W2L[HID * 41];   // [k][class], stride 41: (8c+5g) mod 32 = 2 lanes/bank (free)
    for (int i = threadIdx.x; i < HID * NCLS; i += 256) {
        int j = i / NCLS, k = i % NCLS;
        W2L[j * 41 + k] = W2[i];
    }
    __syncthreads();

    int d = blockIdx.x * 4 + (threadIdx.x >> 6);
    if (d >= n) return;
    int lane = threadIdx.x & 63;
    int g = lane >> 3;        // edge slot 0..7 (later: class-chunk index)
    int c = lane & 7;         // column octet 0..7 (8 bf16 = 16B)
    int2 se = rse[d];
    int start = se.x, end = se.y;
    uint4 selfv = *(const uint4*)&xws[(size_t)d * HID + c * 8];
    float acc[8];
#pragma unroll
    for (int i = 0; i < 8; i++) acc[i] = 0.f;
    for (int j = start; j < end; j += 32) {
#pragma unroll
        for (int t = 0; t < 4; t++) {
            int e = j + t * 8 + g;
            if (e < end) {
                int s = col[e];
                uint4 v = *(const uint4*)&xws[(size_t)s * HID + c * 8];
                acc[0] += bflo(v.x); acc[1] += bfhi(v.x);
                acc[2] += bflo(v.y); acc[3] += bfhi(v.y);
                acc[4] += bflo(v.z); acc[5] += bfhi(v.z);
                acc[6] += bflo(v.w); acc[7] += bfhi(v.w);
            }
        }
    }
#pragma unroll
    for (int off = 8; off <= 32; off <<= 1) {
#pragma unroll
        for (int i = 0; i < 8; i++) acc[i] += __shfl_xor(acc[i], off);
    }
    // all lanes: add self, finish h (f32), pre-scale by dinv for layer 2
    acc[0] += bflo(selfv.x); acc[1] += bfhi(selfv.x);
    acc[2] += bflo(selfv.y); acc[3] += bfhi(selfv.y);
    acc[4] += bflo(selfv.z); acc[5] += bfhi(selfv.z);
    acc[6] += bflo(selfv.w); acc[7] += bfhi(selfv.w);
    float di = dinv[d];
    float4 b0 = *(const float4*)&b1[c * 8];
    float4 b4 = *(const float4*)&b1[c * 8 + 4];
    float hv[8];
    hv[0] = fmaxf(di * acc[0] + b0.x, 0.f) * di;
    hv[1] = fmaxf(di * acc[1] + b0.y, 0.f) * di;
    hv[2] = fmaxf(di * acc[2] + b0.z, 0.f) * di;
    hv[3] = fmaxf(di * acc[3] + b0.w, 0.f) * di;
    hv[4] = fmaxf(di * acc[4] + b4.x, 0.f) * di;
    hv[5] = fmaxf(di * acc[5] + b4.y, 0.f) * di;
    hv[6] = fmaxf(di * acc[6] + b4.z, 0.f) * di;
    hv[7] = fmaxf(di * acc[7] + b4.w, 0.f) * di;

    // matvec: lane (g,c) computes classes k = g*5+kk over its 8 h-dims, reduce across c
    float o[5];
#pragma unroll
    for (int kk = 0; kk < 5; kk++) {
        float s = 0.f;
#pragma unroll
        for (int i = 0; i < 8; i++)
            s += hv[i] * W2L[(c * 8 + i) * 41 + g * 5 + kk];
        o[kk] = s;
    }
#pragma unroll
    for (int off = 1; off < 8; off <<= 1) {
#pragma unroll
        for (int kk = 0; kk < 5; kk++) o[kk] += __shfl_xor(o[kk], off);
    }
    if (c == 0) {
        size_t base = (size_t)d * NCLS + g * 5;
#pragma unroll
        for (int kk = 0; kk < 5; kk++) zs[base + kk] = f2bf(o[kk]);
    }
}

// ============ agg2: out[d] = dinv[d]*(Σ zs[s] + zs[d]) + b2, then log_softmax ============
// 80 B rows: 5 active octet lanes (c<5), classes = c*8+i.
__global__ __launch_bounds__(256) void agg2_lsm_kernel(const ushort_t* __restrict__ zs,
                                                       const int* __restrict__ col,
                                                       const int2* __restrict__ rse,
                                                       const float* __restrict__ dinv,
                                                       const float* __restrict__ b2,
                                                       float* __restrict__ out, int n) {
    int d = blockIdx.x * 4 + (threadIdx.x >> 6);
    if (d >= n) return;
    int lane = threadIdx.x & 63;
    int g = lane >> 3;        // edge slot 0..7
    int c = lane & 7;         // column octet 0..7 (only 0..4 carry data)
    int2 se = rse[d];
    int start = se.x, end = se.y;
    bool act = (c < 5);
    uint4 selfv = make_uint4(0, 0, 0, 0);
    if (act) selfv = *(const uint4*)&zs[(size_t)d * NCLS + c * 8];
    float acc[8];
#pragma unroll
    for (int i = 0; i < 8; i++) acc[i] = 0.f;
    for (int j = start; j < end; j += 32) {
#pragma unroll
        for (int t = 0; t < 4; t++) {
            int e = j + t * 8 + g;
            if (e < end && act) {
                int s = col[e];
                uint4 v = *(const uint4*)&zs[(size_t)s * NCLS + c * 8];
                acc[0] += bflo(v.x); acc[1] += bfhi(v.x);
                acc[2] += bflo(v.y); acc[3] += bfhi(v.y);
                acc[4] += bflo(v.z); acc[5] += bfhi(v.z);
                acc[6] += bflo(v.w); acc[7] += bfhi(v.w);
            }
        }
    }
#pragma unroll
    for (int off = 8; off <= 32; off <<= 1) {
#pragma unroll
        for (int i = 0; i < 8; i++) acc[i] += __shfl_xor(acc[i], off);
    }
    acc[0] += bflo(selfv.x); acc[1] += bfhi(selfv.x);
    acc[2] += bflo(selfv.y); acc[3] += bfhi(selfv.y);
    acc[4] += bflo(selfv.z); acc[5] += bfhi(selfv.z);
    acc[6] += bflo(selfv.w); acc[7] += bfhi(selfv.w);

    float di = dinv[d];
    float4 b0 = make_float4(0.f, 0.f, 0.f, 0.f);
    float4 b4 = make_float4(0.f, 0.f, 0.f, 0.f);
    if (act) {
        b0 = *(const float4*)&b2[c * 8];
        b4 = *(const float4*)&b2[c * 8 + 4];
    }
    float v[8];
    v[0] = di * acc[0] + b0.x; v[1] = di * acc[1] + b0.y;
    v[2] = di * acc[2] + b0.z; v[3] = di * acc[3] + b0.w;
    v[4] = di * acc[4] + b4.x; v[5] = di * acc[5] + b4.y;
    v[6] = di * acc[6] + b4.z; v[7] = di * acc[7] + b4.w;

    float m8 = -INFINITY;
    if (act) {
        m8 = fmaxf(fmaxf(fmaxf(v[0], v[1]), fmaxf(v[2], v[3])),
                   fmaxf(fmaxf(v[4], v[5]), fmaxf(v[6], v[7])));
    }
#pragma unroll
    for (int off = 1; off < 8; off <<= 1) m8 = fmaxf(m8, __shfl_xor(m8, off));
    float s8 = 0.f;
    if (act) {
        s8 = __expf(v[0] - m8) + __expf(v[1] - m8) + __expf(v[2] - m8) + __expf(v[3] - m8)
           + __expf(v[4] - m8) + __expf(v[5] - m8) + __expf(v[6] - m8) + __expf(v[7] - m8);
    }
#pragma unroll
    for (int off = 1; off < 8; off <<= 1) s8 += __shfl_xor(s8, off);

    if (act && g == 0) {
        float lg = __logf(s8);
        float* lsm    = out;
        float* logits = out + (size_t)N_NODES * NCLS;
        float4 lo = make_float4(v[0], v[1], v[2], v[3]);
        float4 hi = make_float4(v[4], v[5], v[6], v[7]);
        *(float4*)&logits[(size_t)d * NCLS + c * 8]     = lo;
        *(float4*)&logits[(size_t)d * NCLS + c * 8 + 4] = hi;
        float4 olo, ohi;
        olo.x = v[0] - m8 - lg; olo.y = v[1] - m8 - lg;
        olo.z = v[2] - m8 - lg; olo.w = v[3] - m8 - lg;
        ohi.x = v[4] - m8 - lg; ohi.y = v[5] - m8 - lg;
        ohi.z = v[6] - m8 - lg; ohi.w = v[7] - m8 - lg;
        *(float4*)&lsm[(size_t)d * NCLS + c * 8]     = olo;
        *(float4*)&lsm[(size_t)d * NCLS + c * 8 + 4] = ohi;
    }
}

extern "C" void kernel_launch(void* const* d_in, const int* in_sizes, int n_in,
                              void* d_out, int out_size, void* d_ws, size_t ws_size,
                              hipStream_t stream) {
    const float* x  = (const float*)d_in[0];
    const int*   ei = (const int*)d_in[1];
    const float* W1 = (const float*)d_in[2];
    const float* b1 = (const float*)d_in[3];
    const float* W2 = (const float*)d_in[4];
    const float* b2 = (const float*)d_in[5];

    const int N = N_NODES;
    const int E = in_sizes[1] / 2;
    const int* src = ei;
    const int* dst = ei + E;

    // workspace layout
    ushort_t* xws  = (ushort_t*)d_ws;                  // N*64 bf16 (pre-scaled by dinv)
    ushort_t* zsb  = xws + (size_t)N * HID;            // N*40 bf16 ((h*dinv) @ W2)
    ushort_t* W1T  = zsb + (size_t)N * NCLS;           // 64*512
    float* dinv    = (float*)(W1T + (size_t)HID * 512);// N
    int2*  rse     = (int2*)(dinv + N);                // N (start,end)
    int*   bcount  = (int*)(rse + N);                  // 512
    int*   pairs   = bcount + 512;                     // NBKT*CAP slabs
    int*   col     = pairs + (size_t)NBKT * CAP;       // NBKT*CAP slabs

    const int NB_W = (N + 3) / 4;

    // 0. zero per-bucket counts
    (void)hipMemsetAsync(bcount, 0, 512 * sizeof(int), stream);

    // 1. fill ∥ W1T prep
    k1_fill_prep<<<FILL_BLKS + PREP_BLKS, 256, 0, stream>>>(src, dst, bcount, pairs, W1, W1T, E);

    // 2. per-bucket CSR finalize (rse, col, dinv)
    b_fine_kernel<<<NBKT, 256, 0, stream>>>(pairs, bcount, rse, col, dinv, N);

    // 3. layer 1 GEMM (pre-scaled by dinv)
    gemm1_mfma<<<GEMM_BLKS, 256, 0, stream>>>(x, W1T, dinv, xws, N);

    // 4. agg1 + relu + fused W2 matvec -> zs (80 B rows)
    agg1z_kernel<<<NB_W, 256, 0, stream>>>(xws, col, rse, dinv, b1, W2, zsb, N);

    // 5. agg2 + bias + log_softmax
    agg2_lsm_kernel<<<NB_W, 256, 0, stream>>>(zsb, col, rse, dinv, b2, (float*)d_out, N);
}

// Round 8
// 475.803 us; speedup vs baseline: 1.0815x; 1.0815x over previous
//
#include <hip/hip_runtime.h>
#include <hip/hip_bf16.h>
#include <math.h>

#define N_NODES 100000
#define F_IN    500
#define HID     64
#define NCLS    40                         // zs rows: 40 cols = 80 B, 16B-aligned
#define NBKT    ((N_NODES + 255) / 256)    // 391 coarse buckets of 256 nodes
#define CAP     8192                       // static slab capacity per bucket (mean 4096)
#define FILL_BLKS 512
#define PREP_ELEMS (HID * 512 + NCLS * HID) // 32768 W1T + 2560 W2bt = 35328
#define PREP_BLKS ((PREP_ELEMS + 255) / 256) // 138
#define GEMM_BLKS ((N_NODES + 127) / 128)  // 782

typedef __attribute__((ext_vector_type(8))) short short8v;
typedef __attribute__((ext_vector_type(4))) float floatx4;
typedef unsigned short ushort_t;
typedef unsigned int uint_t;

__device__ __forceinline__ float bflo(uint_t u) {
    union { uint_t i; float f; } v; v.i = u << 16; return v.f;
}
__device__ __forceinline__ float bfhi(uint_t u) {
    union { uint_t i; float f; } v; v.i = u & 0xffff0000u; return v.f;
}
__device__ __forceinline__ ushort_t f2bf(float f) {
    __hip_bfloat16 b = __float2bfloat16(f);
    return *(ushort_t*)&b;
}
__device__ __forceinline__ uint_t pack2(float a, float b) {
    return (uint_t)f2bf(a) | ((uint_t)f2bf(b) << 16);
}

// ============ kernel 1: fill (blocks [0,FILL_BLKS)) ∥ weight prep (rest) ============
// bcount must be zeroed (hipMemsetAsync) before this kernel.
__global__ __launch_bounds__(256) void k1_fill_prep(const int* __restrict__ src,
                                                    const int* __restrict__ dst,
                                                    int* __restrict__ bcount,
                                                    int* __restrict__ pairs,
                                                    const float* __restrict__ W1,
                                                    ushort_t* __restrict__ W1T,
                                                    const float* __restrict__ W2,
                                                    ushort_t* __restrict__ W2bt, int E) {
    if (blockIdx.x >= FILL_BLKS) {
        int idx = (blockIdx.x - FILL_BLKS) * 256 + threadIdx.x;   // 0..35327
        if (idx < HID * 512) {
            // W1 transpose -> bf16, K padded to 512
            int nn = idx >> 9;
            int k  = idx & 511;
            float v = (k < F_IN) ? W1[(size_t)k * HID + nn] : 0.0f;
            W1T[idx] = f2bf(v);
        } else if (idx < PREP_ELEMS) {
            // W2 transpose -> bf16, rows = class (40), cols = k (64)
            int idx2 = idx - HID * 512;       // 0..2559
            int nc = idx2 >> 6;               // 0..39
            int k  = idx2 & 63;
            W2bt[idx2] = f2bf(W2[(size_t)k * NCLS + nc]);
        }
        return;
    }
    // ---- fill: count + reserve + scatter into static slabs ----
    __shared__ int c[NBKT];
    __shared__ int base[NBKT];
    for (int i = threadIdx.x; i < NBKT; i += 256) c[i] = 0;
    __syncthreads();
    int chunk = (E + FILL_BLKS - 1) / FILL_BLKS;
    int lo = blockIdx.x * chunk;
    int hi = min(lo + chunk, E);
    for (int e = lo + threadIdx.x; e < hi; e += 256) atomicAdd(&c[dst[e] >> 8], 1);
    __syncthreads();
    for (int i = threadIdx.x; i < NBKT; i += 256) {
        int nn = c[i];
        base[i] = nn ? (i * CAP + atomicAdd(&bcount[i], nn)) : 0;
    }
    __syncthreads();
    for (int i = threadIdx.x; i < NBKT; i += 256) c[i] = 0;
    __syncthreads();
    for (int e = lo + threadIdx.x; e < hi; e += 256) {
        int d = dst[e];
        int b = d >> 8;
        int p = base[b] + atomicAdd(&c[b], 1);
        // defensive: never write outside this bucket's slab
        if (p < (b + 1) * CAP) pairs[p] = src[e] | ((d & 255) << 17);   // src < 2^17
    }
}

// ============ b_fine: per-bucket CSR finalize ============
__global__ __launch_bounds__(256) void b_fine_kernel(const int* __restrict__ pairs,
                                                     const int* __restrict__ bcount,
                                                     int2* __restrict__ rse,
                                                     int* __restrict__ col,
                                                     float* __restrict__ dinv, int n) {
    __shared__ int w[CAP];
    __shared__ int cnt[256];
    __shared__ int scn[256];
    __shared__ int cur[256];
    int b = blockIdx.x;
    int nb0 = b << 8;
    int nodes = min(256, n - nb0);
    int g0 = b * CAP;
    int size = min(bcount[b], CAP);
    int tid = threadIdx.x;

    for (int i = tid; i < size; i += 256) w[i] = pairs[g0 + i];
    cnt[tid] = 0;
    __syncthreads();
    for (int i = tid; i < size; i += 256) atomicAdd(&cnt[w[i] >> 17], 1);
    __syncthreads();
    int v = cnt[tid];
    scn[tid] = v;
    __syncthreads();
    for (int off = 1; off < 256; off <<= 1) {
        int t = (tid >= off) ? scn[tid - off] : 0;
        __syncthreads();
        scn[tid] += t;
        __syncthreads();
    }
    int excl = scn[tid] - v;
    cur[tid] = g0 + excl;
    if (tid < nodes) {
        rse[nb0 + tid] = make_int2(g0 + excl, g0 + excl + v);
        dinv[nb0 + tid] = rsqrtf((float)(v + 1));
    }
    __syncthreads();
    for (int i = tid; i < size; i += 256) {
        int word = w[i];
        int pos = atomicAdd(&cur[word >> 17], 1);
        col[pos] = word & 0x1FFFF;
    }
}

// ============ GEMM1 (MFMA bf16, double-buffered): xws = (x @ W1)*dinv, bf16 ============
__global__ __launch_bounds__(256) void gemm1_mfma(const float* __restrict__ x,
                                                  const ushort_t* __restrict__ W1T,
                                                  const float* __restrict__ dinv,
                                                  ushort_t* __restrict__ xws, int n) {
    __shared__ __align__(16) ushort_t As[2][128 * 72];
    const int tid  = threadIdx.x;
    const int wave = tid >> 6;
    const int lane = tid & 63;
    const int m16  = lane & 15;
    const int q    = lane >> 4;
    const int r0   = blockIdx.x * 128;

    floatx4 acc[2][4];
#pragma unroll
    for (int i = 0; i < 2; i++)
#pragma unroll
        for (int j = 0; j < 4; j++) acc[i][j] = (floatx4){0.f, 0.f, 0.f, 0.f};

    const int kg    = tid & 15;   // k-quad (4 floats)
    const int rbase = tid >> 4;   // 0..15

    floatx4 pf[8];
    const floatx4 zero4 = (floatx4){0.f, 0.f, 0.f, 0.f};
    {
        const int k4 = kg * 4;
#pragma unroll
        for (int rr = 0; rr < 8; rr++) {
            int gr = r0 + rbase + rr * 16;
            pf[rr] = (gr < n) ? __builtin_nontemporal_load((const floatx4*)&x[(size_t)gr * F_IN + k4])
                              : zero4;
        }
#pragma unroll
        for (int rr = 0; rr < 8; rr++) {
            int row = rbase + rr * 16;
            *(uint2*)&As[0][row * 72 + kg * 4] =
                make_uint2(pack2(pf[rr][0], pf[rr][1]), pack2(pf[rr][2], pf[rr][3]));
        }
    }
    __syncthreads();

    for (int it = 0; it < 8; it++) {
        const int cur = it & 1;
        if (it < 7) {
            const int k4 = (it + 1) * 64 + kg * 4;
            const bool kok = (k4 < F_IN);
#pragma unroll
            for (int rr = 0; rr < 8; rr++) {
                int gr = r0 + rbase + rr * 16;
                pf[rr] = (kok && gr < n)
                           ? __builtin_nontemporal_load((const floatx4*)&x[(size_t)gr * F_IN + k4])
                           : zero4;
            }
        }
        const int kb = it * 64;
#pragma unroll
        for (int kt = 0; kt < 2; kt++) {
            const int ko = kt * 32 + q * 8;
            short8v a0 = *(const short8v*)&As[cur][(wave * 32 + m16) * 72 + ko];
            short8v a1 = *(const short8v*)&As[cur][(wave * 32 + 16 + m16) * 72 + ko];
#pragma unroll
            for (int nt = 0; nt < 4; nt++) {
                short8v b = *(const short8v*)&W1T[(size_t)(nt * 16 + m16) * 512 + kb + ko];
                acc[0][nt] = __builtin_amdgcn_mfma_f32_16x16x32_bf16(a0, b, acc[0][nt], 0, 0, 0);
                acc[1][nt] = __builtin_amdgcn_mfma_f32_16x16x32_bf16(a1, b, acc[1][nt], 0, 0, 0);
            }
        }
        if (it < 7) {
#pragma unroll
            for (int rr = 0; rr < 8; rr++) {
                int row = rbase + rr * 16;
                *(uint2*)&As[1 - cur][row * 72 + kg * 4] =
                    make_uint2(pack2(pf[rr][0], pf[rr][1]), pack2(pf[rr][2], pf[rr][3]));
            }
            __syncthreads();
        }
    }

    // epilogue: write dinv-PRE-SCALED bf16
#pragma unroll
    for (int mt = 0; mt < 2; mt++) {
#pragma unroll
        for (int i = 0; i < 4; i++) {
            int gr = r0 + wave * 32 + mt * 16 + q * 4 + i;
            if (gr < n) {
                float di = dinv[gr];
#pragma unroll
                for (int nt = 0; nt < 4; nt++) {
                    xws[(size_t)gr * HID + nt * 16 + m16] = f2bf(acc[mt][nt][i] * di);
                }
            }
        }
    }
}

// ============ agg1: hs[d] = relu(dinv[d]*(Σ xws[s] + xws[d]) + b1) * dinv[d], bf16 ============
__global__ __launch_bounds__(256) void agg1_kernel(const ushort_t* __restrict__ xws,
                                                   const int* __restrict__ col,
                                                   const int2* __restrict__ rse,
                                                   const float* __restrict__ dinv,
                                                   const float* __restrict__ b1,
                                                   ushort_t* __restrict__ hs, int n) {
    int d = blockIdx.x * 4 + (threadIdx.x >> 6);
    if (d >= n) return;
    int lane = threadIdx.x & 63;
    int g = lane >> 3;        // edge slot 0..7
    int c = lane & 7;         // column octet 0..7 (8 bf16 = 16B)
    int2 se = rse[d];
    int start = se.x, end = se.y;
    uint4 selfv = *(const uint4*)&xws[(size_t)d * HID + c * 8];
    float acc[8];
#pragma unroll
    for (int i = 0; i < 8; i++) acc[i] = 0.f;
    for (int j = start; j < end; j += 32) {
#pragma unroll
        for (int t = 0; t < 4; t++) {
            int e = j + t * 8 + g;
            if (e < end) {
                int s = col[e];
                uint4 v = *(const uint4*)&xws[(size_t)s * HID + c * 8];
                acc[0] += bflo(v.x); acc[1] += bfhi(v.x);
                acc[2] += bflo(v.y); acc[3] += bfhi(v.y);
                acc[4] += bflo(v.z); acc[5] += bfhi(v.z);
                acc[6] += bflo(v.w); acc[7] += bfhi(v.w);
            }
        }
    }
#pragma unroll
    for (int off = 8; off <= 32; off <<= 1) {
#pragma unroll
        for (int i = 0; i < 8; i++) acc[i] += __shfl_xor(acc[i], off);
    }
    if (g == 0) {
        float di = dinv[d];
        acc[0] += bflo(selfv.x); acc[1] += bfhi(selfv.x);
        acc[2] += bflo(selfv.y); acc[3] += bfhi(selfv.y);
        acc[4] += bflo(selfv.z); acc[5] += bfhi(selfv.z);
        acc[6] += bflo(selfv.w); acc[7] += bfhi(selfv.w);
        float4 b0 = *(const float4*)&b1[c * 8];
        float4 b4 = *(const float4*)&b1[c * 8 + 4];
        uint4 o;
        o.x = pack2(fmaxf(di * acc[0] + b0.x, 0.f) * di, fmaxf(di * acc[1] + b0.y, 0.f) * di);
        o.y = pack2(fmaxf(di * acc[2] + b0.z, 0.f) * di, fmaxf(di * acc[3] + b0.w, 0.f) * di);
        o.z = pack2(fmaxf(di * acc[4] + b4.x, 0.f) * di, fmaxf(di * acc[5] + b4.y, 0.f) * di);
        o.w = pack2(fmaxf(di * acc[6] + b4.z, 0.f) * di, fmaxf(di * acc[7] + b4.w, 0.f) * di);
        *(uint4*)&hs[(size_t)d * HID + c * 8] = o;
    }
}

// ============ GEMM2 (MFMA bf16): zs = hs @ W2, compact 40 cols (80 B rows) ============
__global__ __launch_bounds__(256) void gemm2_mfma(const ushort_t* __restrict__ hs,
                                                  const ushort_t* __restrict__ W2bt,
                                                  ushort_t* __restrict__ zs, int n) {
    int wave = threadIdx.x >> 6, lane = threadIdx.x & 63;
    int m16 = lane & 15, q = lane >> 4;
    int r0 = (blockIdx.x * 4 + wave) * 16;
    if (r0 >= n) return;
    floatx4 acc[3];
#pragma unroll
    for (int nt = 0; nt < 3; nt++) acc[nt] = (floatx4){0.f, 0.f, 0.f, 0.f};
#pragma unroll
    for (int kt = 0; kt < 2; kt++) {
        short8v a = *(const short8v*)&hs[(size_t)(r0 + m16) * HID + kt * 32 + q * 8];
#pragma unroll
        for (int nt = 0; nt < 3; nt++) {
            // W2bt row nc is zero-padded via prep only for nc<40; nt*16+m16 can reach 47:
            // guard the load with a zero vector for nc>=40.
            int nc = nt * 16 + m16;
            short8v b;
            if (nc < NCLS) b = *(const short8v*)&W2bt[(size_t)nc * HID + kt * 32 + q * 8];
            else b = (short8v){0, 0, 0, 0, 0, 0, 0, 0};
            acc[nt] = __builtin_amdgcn_mfma_f32_16x16x32_bf16(a, b, acc[nt], 0, 0, 0);
        }
    }
#pragma unroll
    for (int i = 0; i < 4; i++) {
        int gr = r0 + q * 4 + i;
#pragma unroll
        for (int nt = 0; nt < 3; nt++) {
            int cc = nt * 16 + m16;
            if (cc < NCLS) zs[(size_t)gr * NCLS + cc] = f2bf(acc[nt][i]);
        }
    }
}

// ============ agg2: out[d] = dinv[d]*(Σ zs[s] + zs[d]) + b2, then log_softmax ============
// 80 B rows: 5 active octet lanes (c<5), classes = c*8+i.
__global__ __launch_bounds__(256) void agg2_lsm_kernel(const ushort_t* __restrict__ zs,
                                                       const int* __restrict__ col,
                                                       const int2* __restrict__ rse,
                                                       const float* __restrict__ dinv,
                                                       const float* __restrict__ b2,
                                                       float* __restrict__ out, int n) {
    int d = blockIdx.x * 4 + (threadIdx.x >> 6);
    if (d >= n) return;
    int lane = threadIdx.x & 63;
    int g = lane >> 3;        // edge slot 0..7
    int c = lane & 7;         // column octet 0..7 (only 0..4 carry data)
    int2 se = rse[d];
    int start = se.x, end = se.y;
    bool act = (c < 5);
    uint4 selfv = make_uint4(0, 0, 0, 0);
    if (act) selfv = *(const uint4*)&zs[(size_t)d * NCLS + c * 8];
    float acc[8];
#pragma unroll
    for (int i = 0; i < 8; i++) acc[i] = 0.f;
    for (int j = start; j < end; j += 32) {
#pragma unroll
        for (int t = 0; t < 4; t++) {
            int e = j + t * 8 + g;
            if (e < end && act) {
                int s = col[e];
                uint4 v = *(const uint4*)&zs[(size_t)s * NCLS + c * 8];
                acc[0] += bflo(v.x); acc[1] += bfhi(v.x);
                acc[2] += bflo(v.y); acc[3] += bfhi(v.y);
                acc[4] += bflo(v.z); acc[5] += bfhi(v.z);
                acc[6] += bflo(v.w); acc[7] += bfhi(v.w);
            }
        }
    }
#pragma unroll
    for (int off = 8; off <= 32; off <<= 1) {
#pragma unroll
        for (int i = 0; i < 8; i++) acc[i] += __shfl_xor(acc[i], off);
    }
    acc[0] += bflo(selfv.x); acc[1] += bfhi(selfv.x);
    acc[2] += bflo(selfv.y); acc[3] += bfhi(selfv.y);
    acc[4] += bflo(selfv.z); acc[5] += bfhi(selfv.z);
    acc[6] += bflo(selfv.w); acc[7] += bfhi(selfv.w);

    float di = dinv[d];
    float4 b0 = make_float4(0.f, 0.f, 0.f, 0.f);
    float4 b4 = make_float4(0.f, 0.f, 0.f, 0.f);
    if (act) {
        b0 = *(const float4*)&b2[c * 8];
        b4 = *(const float4*)&b2[c * 8 + 4];
    }
    float v[8];
    v[0] = di * acc[0] + b0.x; v[1] = di * acc[1] + b0.y;
    v[2] = di * acc[2] + b0.z; v[3] = di * acc[3] + b0.w;
    v[4] = di * acc[4] + b4.x; v[5] = di * acc[5] + b4.y;
    v[6] = di * acc[6] + b4.z; v[7] = di * acc[7] + b4.w;

    float m8 = -INFINITY;
    if (act) {
        m8 = fmaxf(fmaxf(fmaxf(v[0], v[1]), fmaxf(v[2], v[3])),
                   fmaxf(fmaxf(v[4], v[5]), fmaxf(v[6], v[7])));
    }
#pragma unroll
    for (int off = 1; off < 8; off <<= 1) m8 = fmaxf(m8, __shfl_xor(m8, off));
    float s8 = 0.f;
    if (act) {
        s8 = __expf(v[0] - m8) + __expf(v[1] - m8) + __expf(v[2] - m8) + __expf(v[3] - m8)
           + __expf(v[4] - m8) + __expf(v[5] - m8) + __expf(v[6] - m8) + __expf(v[7] - m8);
    }
#pragma unroll
    for (int off = 1; off < 8; off <<= 1) s8 += __shfl_xor(s8, off);

    if (act && g == 0) {
        float lg = __logf(s8);
        float* lsm    = out;
        float* logits = out + (size_t)N_NODES * NCLS;
        float4 lo = make_float4(v[0], v[1], v[2], v[3]);
        float4 hi = make_float4(v[4], v[5], v[6], v[7]);
        *(float4*)&logits[(size_t)d * NCLS + c * 8]     = lo;
        *(float4*)&logits[(size_t)d * NCLS + c * 8 + 4] = hi;
        float4 olo, ohi;
        olo.x = v[0] - m8 - lg; olo.y = v[1] - m8 - lg;
        olo.z = v[2] - m8 - lg; olo.w = v[3] - m8 - lg;
        ohi.x = v[4] - m8 - lg; ohi.y = v[5] - m8 - lg;
        ohi.z = v[6] - m8 - lg; ohi.w = v[7] - m8 - lg;
        *(float4*)&lsm[(size_t)d * NCLS + c * 8]     = olo;
        *(float4*)&lsm[(size_t)d * NCLS + c * 8 + 4] = ohi;
    }
}

extern "C" void kernel_launch(void* const* d_in, const int* in_sizes, int n_in,
                              void* d_out, int out_size, void* d_ws, size_t ws_size,
                              hipStream_t stream) {
    const float* x  = (const float*)d_in[0];
    const int*   ei = (const int*)d_in[1];
    const float* W1 = (const float*)d_in[2];
    const float* b1 = (const float*)d_in[3];
    const float* W2 = (const float*)d_in[4];
    const float* b2 = (const float*)d_in[5];

    const int N = N_NODES;
    const int E = in_sizes[1] / 2;
    const int* src = ei;
    const int* dst = ei + E;

    // workspace layout
    ushort_t* xws  = (ushort_t*)d_ws;                  // N*64 bf16 (pre-scaled by dinv)
    ushort_t* hsb  = xws + (size_t)N * HID;            // N*64 bf16 (relu(h)*dinv)
    ushort_t* zsb  = hsb + (size_t)N * HID;            // N*40 bf16 (hs @ W2, compact)
    ushort_t* W1T  = zsb + (size_t)N * NCLS;           // 64*512
    ushort_t* W2bt = W1T + (size_t)HID * 512;          // 40*64
    float* dinv    = (float*)(W2bt + NCLS * HID);      // N
    int2*  rse     = (int2*)(dinv + N);                // N (start,end)
    int*   bcount  = (int*)(rse + N);                  // 512
    int*   pairs   = bcount + 512;                     // NBKT*CAP slabs
    int*   col     = pairs + (size_t)NBKT * CAP;       // NBKT*CAP slabs

    const int NB_W = (N + 3) / 4;

    // 0. zero per-bucket counts
    (void)hipMemsetAsync(bcount, 0, 512 * sizeof(int), stream);

    // 1. fill ∥ weight prep
    k1_fill_prep<<<FILL_BLKS + PREP_BLKS, 256, 0, stream>>>(src, dst, bcount, pairs,
                                                           W1, W1T, W2, W2bt, E);

    // 2. per-bucket CSR finalize (rse, col, dinv)
    b_fine_kernel<<<NBKT, 256, 0, stream>>>(pairs, bcount, rse, col, dinv, N);

    // 3. layer 1 GEMM (pre-scaled by dinv)
    gemm1_mfma<<<GEMM_BLKS, 256, 0, stream>>>(x, W1T, dinv, xws, N);

    // 4. agg1 + relu (+ dest-side dinv pre-scale)
    agg1_kernel<<<NB_W, 256, 0, stream>>>(xws, col, rse, dinv, b1, hsb, N);

    // 5. layer 2 GEMM (compact 40-col zs -> 80 B gather rows)
    gemm2_mfma<<<(N / 16 + 3) / 4, 256, 0, stream>>>(hsb, W2bt, zsb, N);

    // 6. agg2 + bias + log_softmax
    agg2_lsm_kernel<<<NB_W, 256, 0, stream>>>(zsb, col, rse, dinv, b2, (float*)d_out, N);
}

// Round 10
// 441.392 us; speedup vs baseline: 1.1658x; 1.0780x over previous
//
#include <hip/hip_runtime.h>
#include <hip/hip_bf16.h>
#include <math.h>

#define N_NODES 100000
#define F_IN    500
#define HID     64
#define NCLS    40                         // zs rows: 40 cols = 80 B, 16B-aligned
#define NBKT    ((N_NODES + 255) / 256)    // 391 coarse buckets of 256 nodes
#define CAP     8192                       // static slab capacity per bucket (mean 4096)
#define FILL_BLKS 512
#define PREP_ELEMS (HID * 512 + NCLS * HID) // 32768 W1T + 2560 W2bt = 35328
#define PREP_BLKS ((PREP_ELEMS + 255) / 256) // 138
#define GEMM_BLKS ((N_NODES + 127) / 128)  // 782

typedef __attribute__((ext_vector_type(8))) short short8v;
typedef __attribute__((ext_vector_type(4))) float floatx4;
typedef unsigned short ushort_t;
typedef unsigned int uint_t;

__device__ __forceinline__ float bflo(uint_t u) {
    union { uint_t i; float f; } v; v.i = u << 16; return v.f;
}
__device__ __forceinline__ float bfhi(uint_t u) {
    union { uint_t i; float f; } v; v.i = u & 0xffff0000u; return v.f;
}
__device__ __forceinline__ ushort_t f2bf(float f) {
    __hip_bfloat16 b = __float2bfloat16(f);
    return *(ushort_t*)&b;
}
__device__ __forceinline__ uint_t pack2(float a, float b) {
    return (uint_t)f2bf(a) | ((uint_t)f2bf(b) << 16);
}

// ============ kernel 1: fill (blocks [0,FILL_BLKS)) ∥ weight prep (rest) ============
// bcount must be zeroed (hipMemsetAsync) before this kernel.
__global__ __launch_bounds__(256) void k1_fill_prep(const int* __restrict__ src,
                                                    const int* __restrict__ dst,
                                                    int* __restrict__ bcount,
                                                    int* __restrict__ pairs,
                                                    const float* __restrict__ W1,
                                                    ushort_t* __restrict__ W1T,
                                                    const float* __restrict__ W2,
                                                    ushort_t* __restrict__ W2bt, int E) {
    if (blockIdx.x >= FILL_BLKS) {
        int idx = (blockIdx.x - FILL_BLKS) * 256 + threadIdx.x;   // 0..35327
        if (idx < HID * 512) {
            // W1 transpose -> bf16, K padded to 512
            int nn = idx >> 9;
            int k  = idx & 511;
            float v = (k < F_IN) ? W1[(size_t)k * HID + nn] : 0.0f;
            W1T[idx] = f2bf(v);
        } else if (idx < PREP_ELEMS) {
            // W2 transpose -> bf16, rows = class (40), cols = k (64)
            int idx2 = idx - HID * 512;       // 0..2559
            int nc = idx2 >> 6;               // 0..39
            int k  = idx2 & 63;
            W2bt[idx2] = f2bf(W2[(size_t)k * NCLS + nc]);
        }
        return;
    }
    // ---- fill: count + reserve + scatter into static slabs ----
    __shared__ int c[NBKT];
    __shared__ int base[NBKT];
    for (int i = threadIdx.x; i < NBKT; i += 256) c[i] = 0;
    __syncthreads();
    int chunk = (E + FILL_BLKS - 1) / FILL_BLKS;
    int lo = blockIdx.x * chunk;
    int hi = min(lo + chunk, E);
    for (int e = lo + threadIdx.x; e < hi; e += 256) atomicAdd(&c[dst[e] >> 8], 1);
    __syncthreads();
    for (int i = threadIdx.x; i < NBKT; i += 256) {
        int nn = c[i];
        base[i] = nn ? (i * CAP + atomicAdd(&bcount[i], nn)) : 0;
    }
    __syncthreads();
    for (int i = threadIdx.x; i < NBKT; i += 256) c[i] = 0;
    __syncthreads();
    for (int e = lo + threadIdx.x; e < hi; e += 256) {
        int d = dst[e];
        int b = d >> 8;
        int p = base[b] + atomicAdd(&c[b], 1);
        // defensive: never write outside this bucket's slab
        if (p < (b + 1) * CAP) pairs[p] = src[e] | ((d & 255) << 17);   // src < 2^17
    }
}

// ============ b_fine: per-bucket CSR finalize ============
__global__ __launch_bounds__(256) void b_fine_kernel(const int* __restrict__ pairs,
                                                     const int* __restrict__ bcount,
                                                     int2* __restrict__ rse,
                                                     int* __restrict__ col,
                                                     float* __restrict__ dinv, int n) {
    __shared__ int w[CAP];
    __shared__ int cnt[256];
    __shared__ int scn[256];
    __shared__ int cur[256];
    int b = blockIdx.x;
    int nb0 = b << 8;
    int nodes = min(256, n - nb0);
    int g0 = b * CAP;
    int size = min(bcount[b], CAP);
    int tid = threadIdx.x;

    for (int i = tid; i < size; i += 256) w[i] = pairs[g0 + i];
    cnt[tid] = 0;
    __syncthreads();
    for (int i = tid; i < size; i += 256) atomicAdd(&cnt[w[i] >> 17], 1);
    __syncthreads();
    int v = cnt[tid];
    scn[tid] = v;
    __syncthreads();
    for (int off = 1; off < 256; off <<= 1) {
        int t = (tid >= off) ? scn[tid - off] : 0;
        __syncthreads();
        scn[tid] += t;
        __syncthreads();
    }
    int excl = scn[tid] - v;
    cur[tid] = g0 + excl;
    if (tid < nodes) {
        rse[nb0 + tid] = make_int2(g0 + excl, g0 + excl + v);
        dinv[nb0 + tid] = rsqrtf((float)(v + 1));
    }
    __syncthreads();
    for (int i = tid; i < size; i += 256) {
        int word = w[i];
        int pos = atomicAdd(&cur[word >> 17], 1);
        col[pos] = word & 0x1FFFF;
    }
}

// ============ GEMM1 (MFMA bf16, double-buffered): xws = (x @ W1)*dinv, bf16 ============
__global__ __launch_bounds__(256) void gemm1_mfma(const float* __restrict__ x,
                                                  const ushort_t* __restrict__ W1T,
                                                  const float* __restrict__ dinv,
                                                  ushort_t* __restrict__ xws, int n) {
    __shared__ __align__(16) ushort_t As[2][128 * 72];
    const int tid  = threadIdx.x;
    const int wave = tid >> 6;
    const int lane = tid & 63;
    const int m16  = lane & 15;
    const int q    = lane >> 4;
    const int r0   = blockIdx.x * 128;

    floatx4 acc[2][4];
#pragma unroll
    for (int i = 0; i < 2; i++)
#pragma unroll
        for (int j = 0; j < 4; j++) acc[i][j] = (floatx4){0.f, 0.f, 0.f, 0.f};

    const int kg    = tid & 15;   // k-quad (4 floats)
    const int rbase = tid >> 4;   // 0..15

    floatx4 pf[8];
    const floatx4 zero4 = (floatx4){0.f, 0.f, 0.f, 0.f};
    {
        const int k4 = kg * 4;
#pragma unroll
        for (int rr = 0; rr < 8; rr++) {
            int gr = r0 + rbase + rr * 16;
            pf[rr] = (gr < n) ? __builtin_nontemporal_load((const floatx4*)&x[(size_t)gr * F_IN + k4])
                              : zero4;
        }
#pragma unroll
        for (int rr = 0; rr < 8; rr++) {
            int row = rbase + rr * 16;
            *(uint2*)&As[0][row * 72 + kg * 4] =
                make_uint2(pack2(pf[rr][0], pf[rr][1]), pack2(pf[rr][2], pf[rr][3]));
        }
    }
    __syncthreads();

    for (int it = 0; it < 8; it++) {
        const int cur = it & 1;
        if (it < 7) {
            const int k4 = (it + 1) * 64 + kg * 4;
            const bool kok = (k4 < F_IN);
#pragma unroll
            for (int rr = 0; rr < 8; rr++) {
                int gr = r0 + rbase + rr * 16;
                pf[rr] = (kok && gr < n)
                           ? __builtin_nontemporal_load((const floatx4*)&x[(size_t)gr * F_IN + k4])
                           : zero4;
            }
        }
        const int kb = it * 64;
#pragma unroll
        for (int kt = 0; kt < 2; kt++) {
            const int ko = kt * 32 + q * 8;
            short8v a0 = *(const short8v*)&As[cur][(wave * 32 + m16) * 72 + ko];
            short8v a1 = *(const short8v*)&As[cur][(wave * 32 + 16 + m16) * 72 + ko];
#pragma unroll
            for (int nt = 0; nt < 4; nt++) {
                short8v b = *(const short8v*)&W1T[(size_t)(nt * 16 + m16) * 512 + kb + ko];
                acc[0][nt] = __builtin_amdgcn_mfma_f32_16x16x32_bf16(a0, b, acc[0][nt], 0, 0, 0);
                acc[1][nt] = __builtin_amdgcn_mfma_f32_16x16x32_bf16(a1, b, acc[1][nt], 0, 0, 0);
            }
        }
        if (it < 7) {
#pragma unroll
            for (int rr = 0; rr < 8; rr++) {
                int row = rbase + rr * 16;
                *(uint2*)&As[1 - cur][row * 72 + kg * 4] =
                    make_uint2(pack2(pf[rr][0], pf[rr][1]), pack2(pf[rr][2], pf[rr][3]));
            }
            __syncthreads();
        }
    }

    // epilogue: write dinv-PRE-SCALED bf16
#pragma unroll
    for (int mt = 0; mt < 2; mt++) {
#pragma unroll
        for (int i = 0; i < 4; i++) {
            int gr = r0 + wave * 32 + mt * 16 + q * 4 + i;
            if (gr < n) {
                float di = dinv[gr];
#pragma unroll
                for (int nt = 0; nt < 4; nt++) {
                    xws[(size_t)gr * HID + nt * 16 + m16] = f2bf(acc[mt][nt][i] * di);
                }
            }
        }
    }
}

// ============ agg1: 8 lanes/node, 32 nodes/block; no reduction shuffles ============
// hs[d] = relu(dinv[d]*(Σ xws[s] + xws[d]) + b1) * dinv[d], bf16
__global__ __launch_bounds__(256) void agg1_kernel(const ushort_t* __restrict__ xws,
                                                   const int* __restrict__ col,
                                                   const int2* __restrict__ rse,
                                                   const float* __restrict__ dinv,
                                                   const float* __restrict__ b1,
                                                   ushort_t* __restrict__ hs, int n) {
    int d = blockIdx.x * 32 + (threadIdx.x >> 3);
    if (d >= n) return;
    int c = threadIdx.x & 7;      // column octet 0..7 (8 bf16 = 16B), owned end-to-end
    int2 se = rse[d];
    float acc[8];
    uint4 sv = *(const uint4*)&xws[(size_t)d * HID + c * 8];
    acc[0] = bflo(sv.x); acc[1] = bfhi(sv.x);
    acc[2] = bflo(sv.y); acc[3] = bfhi(sv.y);
    acc[4] = bflo(sv.z); acc[5] = bfhi(sv.z);
    acc[6] = bflo(sv.w); acc[7] = bfhi(sv.w);
    int e = se.x;
    for (; e + 4 <= se.y; e += 4) {
        int s0 = col[e], s1 = col[e + 1], s2 = col[e + 2], s3 = col[e + 3];
        uint4 v0 = *(const uint4*)&xws[(size_t)s0 * HID + c * 8];
        uint4 v1 = *(const uint4*)&xws[(size_t)s1 * HID + c * 8];
        uint4 v2 = *(const uint4*)&xws[(size_t)s2 * HID + c * 8];
        uint4 v3 = *(const uint4*)&xws[(size_t)s3 * HID + c * 8];
        acc[0] += bflo(v0.x) + bflo(v1.x) + bflo(v2.x) + bflo(v3.x);
        acc[1] += bfhi(v0.x) + bfhi(v1.x) + bfhi(v2.x) + bfhi(v3.x);
        acc[2] += bflo(v0.y) + bflo(v1.y) + bflo(v2.y) + bflo(v3.y);
        acc[3] += bfhi(v0.y) + bfhi(v1.y) + bfhi(v2.y) + bfhi(v3.y);
        acc[4] += bflo(v0.z) + bflo(v1.z) + bflo(v2.z) + bflo(v3.z);
        acc[5] += bfhi(v0.z) + bfhi(v1.z) + bfhi(v2.z) + bfhi(v3.z);
        acc[6] += bflo(v0.w) + bflo(v1.w) + bflo(v2.w) + bflo(v3.w);
        acc[7] += bfhi(v0.w) + bfhi(v1.w) + bfhi(v2.w) + bfhi(v3.w);
    }
    for (; e < se.y; e++) {
        int s = col[e];
        uint4 v = *(const uint4*)&xws[(size_t)s * HID + c * 8];
        acc[0] += bflo(v.x); acc[1] += bfhi(v.x);
        acc[2] += bflo(v.y); acc[3] += bfhi(v.y);
        acc[4] += bflo(v.z); acc[5] += bfhi(v.z);
        acc[6] += bflo(v.w); acc[7] += bfhi(v.w);
    }
    float di = dinv[d];
    float4 b0 = *(const float4*)&b1[c * 8];
    float4 b4 = *(const float4*)&b1[c * 8 + 4];
    uint4 o;
    o.x = pack2(fmaxf(di * acc[0] + b0.x, 0.f) * di, fmaxf(di * acc[1] + b0.y, 0.f) * di);
    o.y = pack2(fmaxf(di * acc[2] + b0.z, 0.f) * di, fmaxf(di * acc[3] + b0.w, 0.f) * di);
    o.z = pack2(fmaxf(di * acc[4] + b4.x, 0.f) * di, fmaxf(di * acc[5] + b4.y, 0.f) * di);
    o.w = pack2(fmaxf(di * acc[6] + b4.z, 0.f) * di, fmaxf(di * acc[7] + b4.w, 0.f) * di);
    *(uint4*)&hs[(size_t)d * HID + c * 8] = o;
}

// ============ GEMM2 (MFMA bf16): zs = hs @ W2, compact 40 cols (80 B rows) ============
__global__ __launch_bounds__(256) void gemm2_mfma(const ushort_t* __restrict__ hs,
                                                  const ushort_t* __restrict__ W2bt,
                                                  ushort_t* __restrict__ zs, int n) {
    int wave = threadIdx.x >> 6, lane = threadIdx.x & 63;
    int m16 = lane & 15, q = lane >> 4;
    int r0 = (blockIdx.x * 4 + wave) * 16;
    if (r0 >= n) return;
    floatx4 acc[3];
#pragma unroll
    for (int nt = 0; nt < 3; nt++) acc[nt] = (floatx4){0.f, 0.f, 0.f, 0.f};
#pragma unroll
    for (int kt = 0; kt < 2; kt++) {
        short8v a = *(const short8v*)&hs[(size_t)(r0 + m16) * HID + kt * 32 + q * 8];
#pragma unroll
        for (int nt = 0; nt < 3; nt++) {
            int nc = nt * 16 + m16;
            short8v b;
            if (nc < NCLS) b = *(const short8v*)&W2bt[(size_t)nc * HID + kt * 32 + q * 8];
            else b = (short8v){0, 0, 0, 0, 0, 0, 0, 0};
            acc[nt] = __builtin_amdgcn_mfma_f32_16x16x32_bf16(a, b, acc[nt], 0, 0, 0);
        }
    }
#pragma unroll
    for (int i = 0; i < 4; i++) {
        int gr = r0 + q * 4 + i;
#pragma unroll
        for (int nt = 0; nt < 3; nt++) {
            int cc = nt * 16 + m16;
            if (cc < NCLS) zs[(size_t)gr * NCLS + cc] = f2bf(acc[nt][i]);
        }
    }
}

// ============ agg2: 8 lanes/node (5 active octets), fused bias + log_softmax ============
// out[d] = dinv[d]*(Σ zs[s] + zs[d]) + b2 ; softmax reduce over the 8-lane group.
__global__ __launch_bounds__(256) void agg2_lsm_kernel(const ushort_t* __restrict__ zs,
                                                       const int* __restrict__ col,
                                                       const int2* __restrict__ rse,
                                                       const float* __restrict__ dinv,
                                                       const float* __restrict__ b2,
                                                       float* __restrict__ out, int n) {
    int d = blockIdx.x * 32 + (threadIdx.x >> 3);
    if (d >= n) return;
    int c = threadIdx.x & 7;      // octet 0..7; only 0..4 carry data (40 cols = 80 B)
    bool act = (c < 5);
    int2 se = rse[d];
    float acc[8];
#pragma unroll
    for (int i = 0; i < 8; i++) acc[i] = 0.f;
    if (act) {
        uint4 sv = *(const uint4*)&zs[(size_t)d * NCLS + c * 8];
        acc[0] = bflo(sv.x); acc[1] = bfhi(sv.x);
        acc[2] = bflo(sv.y); acc[3] = bfhi(sv.y);
        acc[4] = bflo(sv.z); acc[5] = bfhi(sv.z);
        acc[6] = bflo(sv.w); acc[7] = bfhi(sv.w);
        int e = se.x;
        for (; e + 4 <= se.y; e += 4) {
            int s0 = col[e], s1 = col[e + 1], s2 = col[e + 2], s3 = col[e + 3];
            uint4 v0 = *(const uint4*)&zs[(size_t)s0 * NCLS + c * 8];
            uint4 v1 = *(const uint4*)&zs[(size_t)s1 * NCLS + c * 8];
            uint4 v2 = *(const uint4*)&zs[(size_t)s2 * NCLS + c * 8];
            uint4 v3 = *(const uint4*)&zs[(size_t)s3 * NCLS + c * 8];
            acc[0] += bflo(v0.x) + bflo(v1.x) + bflo(v2.x) + bflo(v3.x);
            acc[1] += bfhi(v0.x) + bfhi(v1.x) + bfhi(v2.x) + bfhi(v3.x);
            acc[2] += bflo(v0.y) + bflo(v1.y) + bflo(v2.y) + bflo(v3.y);
            acc[3] += bfhi(v0.y) + bfhi(v1.y) + bfhi(v2.y) + bfhi(v3.y);
            acc[4] += bflo(v0.z) + bflo(v1.z) + bflo(v2.z) + bflo(v3.z);
            acc[5] += bfhi(v0.z) + bfhi(v1.z) + bfhi(v2.z) + bfhi(v3.z);
            acc[6] += bflo(v0.w) + bflo(v1.w) + bflo(v2.w) + bflo(v3.w);
            acc[7] += bfhi(v0.w) + bfhi(v1.w) + bfhi(v2.w) + bfhi(v3.w);
        }
        for (; e < se.y; e++) {
            int s = col[e];
            uint4 v = *(const uint4*)&zs[(size_t)s * NCLS + c * 8];
            acc[0] += bflo(v.x); acc[1] += bfhi(v.x);
            acc[2] += bflo(v.y); acc[3] += bfhi(v.y);
            acc[4] += bflo(v.z); acc[5] += bfhi(v.z);
            acc[6] += bflo(v.w); acc[7] += bfhi(v.w);
        }
    }

    float di = dinv[d];
    float4 b0 = make_float4(0.f, 0.f, 0.f, 0.f);
    float4 b4 = make_float4(0.f, 0.f, 0.f, 0.f);
    if (act) {
        b0 = *(const float4*)&b2[c * 8];
        b4 = *(const float4*)&b2[c * 8 + 4];
    }
    float v[8];
    v[0] = di * acc[0] + b0.x; v[1] = di * acc[1] + b0.y;
    v[2] = di * acc[2] + b0.z; v[3] = di * acc[3] + b0.w;
    v[4] = di * acc[4] + b4.x; v[5] = di * acc[5] + b4.y;
    v[6] = di * acc[6] + b4.z; v[7] = di * acc[7] + b4.w;

    float m8 = -INFINITY;
    if (act) {
        m8 = fmaxf(fmaxf(fmaxf(v[0], v[1]), fmaxf(v[2], v[3])),
                   fmaxf(fmaxf(v[4], v[5]), fmaxf(v[6], v[7])));
    }
#pragma unroll
    for (int off = 1; off < 8; off <<= 1) m8 = fmaxf(m8, __shfl_xor(m8, off));
    float s8 = 0.f;
    if (act) {
        s8 = __expf(v[0] - m8) + __expf(v[1] - m8) + __expf(v[2] - m8) + __expf(v[3] - m8)
           + __expf(v[4] - m8) + __expf(v[5] - m8) + __expf(v[6] - m8) + __expf(v[7] - m8);
    }
#pragma unroll
    for (int off = 1; off < 8; off <<= 1) s8 += __shfl_xor(s8, off);

    if (act) {
        float lg = __logf(s8);
        float* lsm    = out;
        float* logits = out + (size_t)N_NODES * NCLS;
        float4 lo = make_float4(v[0], v[1], v[2], v[3]);
        float4 hi = make_float4(v[4], v[5], v[6], v[7]);
        *(float4*)&logits[(size_t)d * NCLS + c * 8]     = lo;
        *(float4*)&logits[(size_t)d * NCLS + c * 8 + 4] = hi;
        float4 olo, ohi;
        olo.x = v[0] - m8 - lg; olo.y = v[1] - m8 - lg;
        olo.z = v[2] - m8 - lg; olo.w = v[3] - m8 - lg;
        ohi.x = v[4] - m8 - lg; ohi.y = v[5] - m8 - lg;
        ohi.z = v[6] - m8 - lg; ohi.w = v[7] - m8 - lg;
        *(float4*)&lsm[(size_t)d * NCLS + c * 8]     = olo;
        *(float4*)&lsm[(size_t)d * NCLS + c * 8 + 4] = ohi;
    }
}

extern "C" void kernel_launch(void* const* d_in, const int* in_sizes, int n_in,
                              void* d_out, int out_size, void* d_ws, size_t ws_size,
                              hipStream_t stream) {
    const float* x  = (const float*)d_in[0];
    const int*   ei = (const int*)d_in[1];
    const float* W1 = (const float*)d_in[2];
    const float* b1 = (const float*)d_in[3];
    const float* W2 = (const float*)d_in[4];
    const float* b2 = (const float*)d_in[5];

    const int N = N_NODES;
    const int E = in_sizes[1] / 2;
    const int* src = ei;
    const int* dst = ei + E;

    // workspace layout
    ushort_t* xws  = (ushort_t*)d_ws;                  // N*64 bf16 (pre-scaled by dinv)
    ushort_t* hsb  = xws + (size_t)N * HID;            // N*64 bf16 (relu(h)*dinv)
    ushort_t* zsb  = hsb + (size_t)N * HID;            // N*40 bf16 (hs @ W2, compact)
    ushort_t* W1T  = zsb + (size_t)N * NCLS;           // 64*512
    ushort_t* W2bt = W1T + (size_t)HID * 512;          // 40*64
    float* dinv    = (float*)(W2bt + NCLS * HID);      // N
    int2*  rse     = (int2*)(dinv + N);                // N (start,end)
    int*   bcount  = (int*)(rse + N);                  // 512
    int*   pairs   = bcount + 512;                     // NBKT*CAP slabs
    int*   col     = pairs + (size_t)NBKT * CAP;       // NBKT*CAP slabs

    const int NB_A = (N + 31) / 32;   // agg kernels: 32 nodes/block

    // 0. zero per-bucket counts
    (void)hipMemsetAsync(bcount, 0, 512 * sizeof(int), stream);

    // 1. fill ∥ weight prep
    k1_fill_prep<<<FILL_BLKS + PREP_BLKS, 256, 0, stream>>>(src, dst, bcount, pairs,
                                                           W1, W1T, W2, W2bt, E);

    // 2. per-bucket CSR finalize (rse, col, dinv)
    b_fine_kernel<<<NBKT, 256, 0, stream>>>(pairs, bcount, rse, col, dinv, N);

    // 3. layer 1 GEMM (pre-scaled by dinv)
    gemm1_mfma<<<GEMM_BLKS, 256, 0, stream>>>(x, W1T, dinv, xws, N);

    // 4. agg1 + relu (8 lanes/node, shuffle-free)
    agg1_kernel<<<NB_A, 256, 0, stream>>>(xws, col, rse, dinv, b1, hsb, N);

    // 5. layer 2 GEMM (compact 40-col zs -> 80 B gather rows)
    gemm2_mfma<<<(N / 16 + 3) / 4, 256, 0, stream>>>(hsb, W2bt, zsb, N);

    // 6. agg2 + bias + log_softmax (8 lanes/node)
    agg2_lsm_kernel<<<NB_A, 256, 0, stream>>>(zsb, col, rse, dinv, b2, (float*)d_out, N);
}